// Round 9
// baseline (379.093 us; speedup 1.0000x reference)
//
#include <hip/hip_runtime.h>
#include <hip/hip_bf16.h>

#define N_NODES 100000
#define N_EDGES 3200000
#define IN_CH   128
#define HID     32
#define NB      512              // dst buckets for CSR build
#define NPB     196              // nodes per bucket (512*196 >= 100000)
#define CAP     8192             // fixed per-bucket region capacity (mean 6250, 24 sigma)
#define CHUNK   8192             // edges per block in bucket_scatter2

// --- bf16x2 pack/unpack (round-to-nearest-even) ----------------------------
__device__ __forceinline__ unsigned int pack_bf16x2(float a, float b) {
    unsigned int ua = __float_as_uint(a);
    unsigned int ub = __float_as_uint(b);
    ua = (ua + 0x7FFFu + ((ua >> 16) & 1u)) >> 16;
    ub = (ub + 0x7FFFu + ((ub >> 16) & 1u)) >> 16;
    return (ua & 0xFFFFu) | (ub << 16);
}
__device__ __forceinline__ float bf_lo(unsigned int v) { return __uint_as_float(v << 16); }
__device__ __forceinline__ float bf_hi(unsigned int v) { return __uint_as_float(v & 0xFFFF0000u); }

// ---------------------------------------------------------------------------
// Detect whether edge_index is int64 (odd 32-bit words all zero) or int32.
// ---------------------------------------------------------------------------
__global__ __launch_bounds__(256) void detect_idx(const int* __restrict__ ei,
                                                  int* __restrict__ flag) {
    __shared__ int nz;
    if (threadIdx.x == 0) nz = 0;
    __syncthreads();
    if (ei[2 * threadIdx.x + 1] != 0) atomicAdd(&nz, 1);
    __syncthreads();
    if (threadIdx.x == 0) flag[0] = (nz == 0) ? 1 : 0;
}

__device__ __forceinline__ int edge_at(const int* __restrict__ ei, int idx64,
                                       size_t pos) {
    if (idx64) return (int)((const long long*)ei)[pos];
    return ei[pos];
}

__global__ __launch_bounds__(256) void bcur_init(int* __restrict__ bcur) {
    int b = blockIdx.x * 256 + threadIdx.x;
    if (b < NB) bcur[b] = b * CAP;
}

// ---------------------------------------------------------------------------
// Scatter edges into fixed-capacity dst-bucket regions of ebuf, 4 B packed
// (s<<8)|dloc. Block-level pre-aggregation keeps global atomics to one per
// (block, nonzero-bucket).
// ---------------------------------------------------------------------------
__global__ __launch_bounds__(256) void bucket_scatter2(
    const int* __restrict__ ei,
    const int* __restrict__ flag,
    int* __restrict__ bcur,
    unsigned int* __restrict__ ebuf) {
    __shared__ unsigned int   pk[CHUNK];     // 32 KB  packed (s<<8)|dloc
    __shared__ unsigned short bb[CHUNK];     // 16 KB  bucket id per edge
    __shared__ int cnt[NB];                  // 2 KB   block histogram
    __shared__ int cnt2[NB];                 // 2 KB   scatter cursor
    __shared__ int base_l[NB];               // 2 KB   reserved global base

    int t = threadIdx.x;
    for (int j = t; j < NB; j += 256) { cnt[j] = 0; cnt2[j] = 0; }
    __syncthreads();

    int e0 = blockIdx.x * CHUNK;
    int nE = N_EDGES - e0; if (nE > CHUNK) nE = CHUNK;
    int idx64 = flag[0];

    for (int i = t; i < nE; i += 256) {
        unsigned int s = (unsigned int)edge_at(ei, idx64, (size_t)(e0 + i));
        unsigned int d = (unsigned int)edge_at(ei, idx64, (size_t)N_EDGES + e0 + i);
        unsigned int b = d / NPB;            // compile-time const -> magic mul
        pk[i] = (s << 8) | (d - b * NPB);
        bb[i] = (unsigned short)b;
        atomicAdd(&cnt[b], 1);               // LDS atomic
    }
    __syncthreads();

    for (int j = t; j < NB; j += 256) {
        int c = cnt[j];
        if (c > 0) base_l[j] = atomicAdd(&bcur[j], c);   // one per bucket
    }
    __syncthreads();

    for (int i = t; i < nE; i += 256) {
        int b = bb[i];
        int p = atomicAdd(&cnt2[b], 1);      // LDS atomic
        ebuf[base_l[b] + p] = pk[i];
    }
}

// ---------------------------------------------------------------------------
// Exclusive scan of the 512 final bucket counts -> gbase (single block).
// ---------------------------------------------------------------------------
__global__ __launch_bounds__(512) void scan_buckets(const int* __restrict__ bcur,
                                                    int* __restrict__ gbase,
                                                    int* __restrict__ rowptr) {
    __shared__ int tmp[512];
    int t = threadIdx.x;
    int c = bcur[t] - t * CAP;               // this bucket's edge count
    tmp[t] = c;
    __syncthreads();
    for (int off = 1; off < 512; off <<= 1) {
        int x = 0;
        if (t >= off) x = tmp[t - off];
        __syncthreads();
        if (t >= off) tmp[t] += x;
        __syncthreads();
    }
    gbase[t] = tmp[t] - c;                   // exclusive
    if (t == 511) rowptr[N_NODES] = N_EDGES;
}

// ---------------------------------------------------------------------------
// Per-bucket finalize: local dst histogram -> dinv, local scan -> rowptr,
// LDS scatter -> coalesced col.
// ---------------------------------------------------------------------------
__global__ __launch_bounds__(256) void fill_csr3(
    const int* __restrict__ bcur,
    const int* __restrict__ gbase,
    const unsigned int* __restrict__ ebuf,
    int* __restrict__ rowptr,
    float* __restrict__ dinv,
    int* __restrict__ col) {
    __shared__ int lhist[NPB];
    __shared__ int lrow[NPB];      // exclusive offsets, then scatter cursors
    __shared__ int tmp[256];
    __shared__ int lbuf[CAP];      // 32 KB
    int b = blockIdx.x;
    int t = threadIdx.x;
    int n0 = b * NPB;  if (n0 > N_NODES) n0 = N_NODES;
    int n1 = n0 + NPB; if (n1 > N_NODES) n1 = N_NODES;
    int nn  = n1 - n0;
    int cnt = bcur[b] - b * CAP;
    int E0  = gbase[b];
    const unsigned int* reg = ebuf + (size_t)b * CAP;

    for (int j = t; j < NPB; j += 256) lhist[j] = 0;
    __syncthreads();
    for (int i = t; i < cnt; i += 256)
        atomicAdd(&lhist[reg[i] & 255u], 1);     // LDS histogram
    __syncthreads();

    // fused make_dinv (self-loop +1)
    for (int j = t; j < nn; j += 256)
        dinv[n0 + j] = rsqrtf((float)(lhist[j] + 1));

    // exclusive scan of lhist[0..nn) (NPB < 256: one Hillis-Steele pass)
    int v = (t < NPB) ? lhist[t] : 0;
    tmp[t] = v;
    __syncthreads();
    for (int off = 1; off < 256; off <<= 1) {
        int x = 0;
        if (t >= off) x = tmp[t - off];
        __syncthreads();
        if (t >= off) tmp[t] += x;
        __syncthreads();
    }
    if (t < NPB) lrow[t] = tmp[t] - v;
    __syncthreads();

    for (int j = t; j < nn; j += 256)
        rowptr[n0 + j] = E0 + lrow[j];
    __syncthreads();               // rowptr reads lrow before cursor mutation

    for (int i = t; i < cnt; i += 256) {
        unsigned int e = reg[i];
        int p = atomicAdd(&lrow[e & 255u], 1);
        lbuf[p] = (int)(e >> 8);
    }
    __syncthreads();
    for (int j = t; j < cnt; j += 256)
        col[E0 + j] = lbuf[j];
}

// ---------------------------------------------------------------------------
// GEMM1: h1b[n][c2] = pack_bf16( (x[n]·W1[:,2c2..2c2+1]) * dinv[n] )
// ---------------------------------------------------------------------------
__global__ __launch_bounds__(256) void gemm1_scale(
    const float* __restrict__ x,
    const float* __restrict__ W1,
    const float* __restrict__ dinv,
    unsigned int* __restrict__ h1b) {
    __shared__ float w[IN_CH * HID];   // 16 KB
    for (int i = threadIdx.x; i < IN_CH * HID; i += 256)
        w[i] = W1[i];
    __syncthreads();

    int node = blockIdx.x * 8 + (threadIdx.x >> 5);
    int c    = threadIdx.x & 31;
    if (node >= N_NODES) return;

    const float4* xr = reinterpret_cast<const float4*>(x + (size_t)node * IN_CH);
    float acc = 0.0f;
#pragma unroll
    for (int k4 = 0; k4 < IN_CH / 4; ++k4) {
        float4 v = xr[k4];
        acc += v.x * w[(k4 * 4 + 0) * HID + c]
             + v.y * w[(k4 * 4 + 1) * HID + c]
             + v.z * w[(k4 * 4 + 2) * HID + c]
             + v.w * w[(k4 * 4 + 3) * HID + c];
    }
    float val = acc * dinv[node];
    int c2 = c & 15;
    float lo = __shfl(val, 2 * c2, 32);
    float hi = __shfl(val, 2 * c2 + 1, 32);
    if (c < 16) h1b[(size_t)node * 16 + c2] = pack_bf16x2(lo, hi);
}

// ---------------------------------------------------------------------------
// Row-gather core: 32-edge chunks. One coalesced col load per chunk per
// 32-group, indices distributed by shfl; each 16-lane half runs a fully
// unrolled 16-deep predicated gather sequence -> up to 16 loads in flight.
// NOTE: the __shfl is UNCONDITIONAL. Inside `if (k < m)` it read from
// exec-masked-off source lanes for odd tails m in [17,31] (ds_bpermute
// honors EXEC on the write phase -> undefined data; caused round-8's
// 3.6e-2 absmax). All 32 lanes execute the shfl; only the gather+add is
// predicated.
// ---------------------------------------------------------------------------
__device__ __forceinline__ void row_gather(
    const int* __restrict__ col, const unsigned int* __restrict__ tab,
    int e0, int e1, int half, int c2,
    float aeA[4], float aoA[4]) {
    for (int base = e0; base < e1; base += 32) {
        int idx = base + (half << 4) + c2;          // = base + lane
        int cv = (idx < e1) ? col[idx] : 0;
        int m = e1 - base;                          // valid edges this chunk
#pragma unroll
        for (int j = 0; j < 16; ++j) {
            int k = 2 * j + half;
            int s = __shfl(cv, k, 32);              // all lanes: sources active
            if (k < m) {
                unsigned int v = tab[(size_t)s * 16 + c2];
                aeA[j & 3] += bf_lo(v);
                aoA[j & 3] += bf_hi(v);
            }
        }
    }
}

// ---------------------------------------------------------------------------
// Layer-1 aggregate (bf16 gather) + relu + gemm2 (shuffles) -> h3b.
// ---------------------------------------------------------------------------
__global__ __launch_bounds__(256) void aggregate1(
    const int* __restrict__ rowptr,
    const int* __restrict__ col,
    const unsigned int* __restrict__ h1b,
    const float* __restrict__ dinv,
    const float* __restrict__ b1,
    const float* __restrict__ W2,
    unsigned int* __restrict__ h3b) {
    __shared__ float w2s[HID * HID];   // 4 KB
    for (int i = threadIdx.x; i < HID * HID; i += 256)
        w2s[i] = W2[i];
    __syncthreads();

    int node = blockIdx.x * 8 + (threadIdx.x >> 5);
    int lane = threadIdx.x & 31;
    if (node >= N_NODES) return;
    int half = lane >> 4;
    int c2   = lane & 15;

    int e0 = rowptr[node];
    int e1 = rowptr[node + 1];
    float aeA[4] = {0.f, 0.f, 0.f, 0.f};
    float aoA[4] = {0.f, 0.f, 0.f, 0.f};
    if (half == 0) {                       // self-loop
        unsigned int sv = h1b[(size_t)node * 16 + c2];
        aeA[0] = bf_lo(sv); aoA[0] = bf_hi(sv);
    }
    row_gather(col, h1b, e0, e1, half, c2, aeA, aoA);

    float ae = (aeA[0] + aeA[1]) + (aeA[2] + aeA[3]);
    float ao = (aoA[0] + aoA[1]) + (aoA[2] + aoA[3]);
    ae += __shfl_xor(ae, 16, 32);          // combine halves
    ao += __shfl_xor(ao, 16, 32);

    float dn = dinv[node];
    float h2e = ae * dn + b1[2 * c2];      h2e = h2e > 0.f ? h2e : 0.f;
    float h2o = ao * dn + b1[2 * c2 + 1];  h2o = h2o > 0.f ? h2o : 0.f;

    // gemm2: lane j (half 0) holds h2[2j], h2[2j+1]; all-to-all via shfl
    float a2e = 0.f, a2o = 0.f;
#pragma unroll
    for (int j = 0; j < 16; ++j) {
        float he = __shfl(h2e, j, 32);     // h2[2j]
        float ho = __shfl(h2o, j, 32);     // h2[2j+1]
        a2e += he * w2s[(2 * j) * HID + 2 * c2]     + ho * w2s[(2 * j + 1) * HID + 2 * c2];
        a2o += he * w2s[(2 * j) * HID + 2 * c2 + 1] + ho * w2s[(2 * j + 1) * HID + 2 * c2 + 1];
    }
    if (half == 0)
        h3b[(size_t)node * 16 + c2] = pack_bf16x2(a2e * dn, a2o * dn);
}

// ---------------------------------------------------------------------------
// Layer-2 aggregate (bf16 gather) + epilogue2 -> f32 out
// ---------------------------------------------------------------------------
__global__ __launch_bounds__(256) void aggregate2(
    const int* __restrict__ rowptr,
    const int* __restrict__ col,
    const unsigned int* __restrict__ h3b,
    const float* __restrict__ dinv,
    const float* __restrict__ b2,
    float2* __restrict__ out2) {
    int node = blockIdx.x * 8 + (threadIdx.x >> 5);
    int lane = threadIdx.x & 31;
    if (node >= N_NODES) return;
    int half = lane >> 4;
    int c2   = lane & 15;

    int e0 = rowptr[node];
    int e1 = rowptr[node + 1];
    float aeA[4] = {0.f, 0.f, 0.f, 0.f};
    float aoA[4] = {0.f, 0.f, 0.f, 0.f};
    if (half == 0) {                       // self-loop
        unsigned int sv = h3b[(size_t)node * 16 + c2];
        aeA[0] = bf_lo(sv); aoA[0] = bf_hi(sv);
    }
    row_gather(col, h3b, e0, e1, half, c2, aeA, aoA);

    float ae = (aeA[0] + aeA[1]) + (aeA[2] + aeA[3]);
    float ao = (aoA[0] + aoA[1]) + (aoA[2] + aoA[3]);
    ae += __shfl_xor(ae, 16, 32);
    ao += __shfl_xor(ao, 16, 32);

    if (half == 0) {
        float dn = dinv[node];
        float2 o;
        o.x = ae * dn + b2[2 * c2];
        o.y = ao * dn + b2[2 * c2 + 1];
        out2[(size_t)node * 16 + c2] = o;
    }
}

// ---------------------------------------------------------------------------
extern "C" void kernel_launch(void* const* d_in, const int* in_sizes, int n_in,
                              void* d_out, int out_size, void* d_ws, size_t ws_size,
                              hipStream_t stream) {
    const float* x  = (const float*)d_in[0];
    const int*   ei = (const int*)d_in[1];
    const float* W1 = (const float*)d_in[2];
    const float* b1 = (const float*)d_in[3];
    const float* W2 = (const float*)d_in[4];
    const float* b2 = (const float*)d_in[5];
    float* out = (float*)d_out;

    // workspace: flag[64] | bcur[512] | gbase[512] | rowptr[N+1] | col[E] |
    //            dinv[N] | region{ h1b (6.4MB) | h3b (6.4MB) } where ebuf
    //            (512*CAP u32 = 16 MiB) ALIASES the region (dead by gemm1).
    // Total ~31 MiB.
    int*          flag   = (int*)d_ws;
    int*          bcur   = flag + 64;
    int*          gbase  = bcur + NB;
    int*          rowptr = gbase + NB;
    int*          col    = rowptr + (N_NODES + 1);
    float*        dinv   = (float*)(col + N_EDGES);
    unsigned int* h1b    = (unsigned int*)(dinv + N_NODES);
    unsigned int* h3b    = h1b + (size_t)N_NODES * 16;
    unsigned int* ebuf   = h1b;                          // alias, dead by gemm1

    const int gemmBlocks  = (N_NODES + 7) / 8;               // 12500
    const int chunkBlocks = (N_EDGES + CHUNK - 1) / CHUNK;   // 391

    detect_idx<<<1, 256, 0, stream>>>(ei, flag);

    // bucketed CSR build (single pass over edge_index)
    bcur_init<<<(NB + 255) / 256, 256, 0, stream>>>(bcur);
    bucket_scatter2<<<chunkBlocks, 256, 0, stream>>>(ei, flag, bcur, ebuf);
    scan_buckets<<<1, 512, 0, stream>>>(bcur, gbase, rowptr);
    fill_csr3<<<NB, 256, 0, stream>>>(bcur, gbase, ebuf, rowptr, dinv, col);

    // layer 1 (+ fused relu + gemm2)
    gemm1_scale<<<gemmBlocks, 256, 0, stream>>>(x, W1, dinv, h1b);
    aggregate1<<<gemmBlocks, 256, 0, stream>>>(rowptr, col, h1b, dinv, b1, W2, h3b);

    // layer 2 (+ fused epilogue)
    aggregate2<<<gemmBlocks, 256, 0, stream>>>(rowptr, col, h3b, dinv, b2, (float2*)out);
}

// Round 10
// 371.181 us; speedup vs baseline: 1.0213x; 1.0213x over previous
//
#include <hip/hip_runtime.h>
#include <hip/hip_bf16.h>

#define N_NODES 100000
#define N_EDGES 3200000
#define IN_CH   128
#define HID     32
#define NB      512              // dst buckets for CSR build
#define NPB     196              // nodes per bucket (512*196 >= 100000)
#define CAP     8192             // fixed per-bucket region capacity (mean 6250, 24 sigma)
#define CHUNK   8192             // edges per block in bucket_scatter2

// --- bf16x2 pack/unpack (round-to-nearest-even) ----------------------------
__device__ __forceinline__ unsigned int pack_bf16x2(float a, float b) {
    unsigned int ua = __float_as_uint(a);
    unsigned int ub = __float_as_uint(b);
    ua = (ua + 0x7FFFu + ((ua >> 16) & 1u)) >> 16;
    ub = (ub + 0x7FFFu + ((ub >> 16) & 1u)) >> 16;
    return (ua & 0xFFFFu) | (ub << 16);
}
__device__ __forceinline__ float bf_lo(unsigned int v) { return __uint_as_float(v << 16); }
__device__ __forceinline__ float bf_hi(unsigned int v) { return __uint_as_float(v & 0xFFFF0000u); }

__device__ __forceinline__ int edge_at(const int* __restrict__ ei, int idx64,
                                       size_t pos) {
    if (idx64) return (int)((const long long*)ei)[pos];
    return ei[pos];
}

// ---------------------------------------------------------------------------
// Fused: int64-vs-int32 detection (odd 32-bit words all zero -> int64) and
// bucket-cursor init. One block, 512 threads. (Was two dispatches.)
// ---------------------------------------------------------------------------
__global__ __launch_bounds__(512) void init_all(const int* __restrict__ ei,
                                                int* __restrict__ flag,
                                                int* __restrict__ bcur) {
    __shared__ int nz;
    int t = threadIdx.x;
    if (t == 0) nz = 0;
    __syncthreads();
    if (t < 256 && ei[2 * t + 1] != 0) atomicAdd(&nz, 1);
    bcur[t] = t * CAP;
    __syncthreads();
    if (t == 0) flag[0] = (nz == 0) ? 1 : 0;
}

// ---------------------------------------------------------------------------
// Scatter edges into fixed-capacity dst-bucket regions of ebuf, 4 B packed
// (s<<8)|dloc. Block-level pre-aggregation keeps global atomics to one per
// (block, nonzero-bucket).
// ---------------------------------------------------------------------------
__global__ __launch_bounds__(256) void bucket_scatter2(
    const int* __restrict__ ei,
    const int* __restrict__ flag,
    int* __restrict__ bcur,
    unsigned int* __restrict__ ebuf) {
    __shared__ unsigned int   pk[CHUNK];     // 32 KB  packed (s<<8)|dloc
    __shared__ unsigned short bb[CHUNK];     // 16 KB  bucket id per edge
    __shared__ int cnt[NB];                  // 2 KB   block histogram
    __shared__ int cnt2[NB];                 // 2 KB   scatter cursor
    __shared__ int base_l[NB];               // 2 KB   reserved global base

    int t = threadIdx.x;
    for (int j = t; j < NB; j += 256) { cnt[j] = 0; cnt2[j] = 0; }
    __syncthreads();

    int e0 = blockIdx.x * CHUNK;
    int nE = N_EDGES - e0; if (nE > CHUNK) nE = CHUNK;
    int idx64 = flag[0];

    for (int i = t; i < nE; i += 256) {
        unsigned int s = (unsigned int)edge_at(ei, idx64, (size_t)(e0 + i));
        unsigned int d = (unsigned int)edge_at(ei, idx64, (size_t)N_EDGES + e0 + i);
        unsigned int b = d / NPB;            // compile-time const -> magic mul
        pk[i] = (s << 8) | (d - b * NPB);
        bb[i] = (unsigned short)b;
        atomicAdd(&cnt[b], 1);               // LDS atomic
    }
    __syncthreads();

    for (int j = t; j < NB; j += 256) {
        int c = cnt[j];
        if (c > 0) base_l[j] = atomicAdd(&bcur[j], c);   // one per bucket
    }
    __syncthreads();

    for (int i = t; i < nE; i += 256) {
        int b = bb[i];
        int p = atomicAdd(&cnt2[b], 1);      // LDS atomic
        ebuf[base_l[b] + p] = pk[i];
    }
}

// ---------------------------------------------------------------------------
// Per-bucket finalize: inline prefix over the 512 bucket counts (replaces
// the scan_buckets dispatch), local dst histogram -> dinv, local scan ->
// rowptr, LDS scatter -> coalesced col.
// ---------------------------------------------------------------------------
__global__ __launch_bounds__(256) void fill_csr3(
    const int* __restrict__ bcur,
    const unsigned int* __restrict__ ebuf,
    int* __restrict__ rowptr,
    float* __restrict__ dinv,
    int* __restrict__ col) {
    __shared__ int lhist[NPB];
    __shared__ int lrow[NPB];      // exclusive offsets, then scatter cursors
    __shared__ int tmp[256];
    __shared__ int lbuf[CAP];      // 32 KB
    int b = blockIdx.x;
    int t = threadIdx.x;

    // --- inline exclusive prefix: E0 = sum of counts of buckets < b --------
    int partial = 0;
    for (int j = t; j < NB; j += 256)
        if (j < b) partial += bcur[j] - j * CAP;
    tmp[t] = partial;
    __syncthreads();
    for (int off = 128; off > 0; off >>= 1) {
        if (t < off) tmp[t] += tmp[t + off];
        __syncthreads();
    }
    int E0 = tmp[0];
    __syncthreads();               // tmp reused below

    int n0 = b * NPB;  if (n0 > N_NODES) n0 = N_NODES;
    int n1 = n0 + NPB; if (n1 > N_NODES) n1 = N_NODES;
    int nn  = n1 - n0;
    int cnt = bcur[b] - b * CAP;
    const unsigned int* reg = ebuf + (size_t)b * CAP;

    for (int j = t; j < NPB; j += 256) lhist[j] = 0;
    __syncthreads();
    for (int i = t; i < cnt; i += 256)
        atomicAdd(&lhist[reg[i] & 255u], 1);     // LDS histogram
    __syncthreads();

    // fused make_dinv (self-loop +1)
    for (int j = t; j < nn; j += 256)
        dinv[n0 + j] = rsqrtf((float)(lhist[j] + 1));

    // exclusive scan of lhist[0..nn) (NPB < 256: one Hillis-Steele pass)
    int v = (t < NPB) ? lhist[t] : 0;
    tmp[t] = v;
    __syncthreads();
    for (int off = 1; off < 256; off <<= 1) {
        int x = 0;
        if (t >= off) x = tmp[t - off];
        __syncthreads();
        if (t >= off) tmp[t] += x;
        __syncthreads();
    }
    if (t < NPB) lrow[t] = tmp[t] - v;
    __syncthreads();

    for (int j = t; j < nn; j += 256)
        rowptr[n0 + j] = E0 + lrow[j];
    if (b == NB - 1 && t == 0) rowptr[N_NODES] = N_EDGES;
    __syncthreads();               // rowptr reads lrow before cursor mutation

    for (int i = t; i < cnt; i += 256) {
        unsigned int e = reg[i];
        int p = atomicAdd(&lrow[e & 255u], 1);
        lbuf[p] = (int)(e >> 8);
    }
    __syncthreads();
    for (int j = t; j < cnt; j += 256)
        col[E0 + j] = lbuf[j];
}

// ---------------------------------------------------------------------------
// GEMM1: h1b[n][c2] = pack_bf16( (x[n]·W1[:,2c2..2c2+1]) * dinv[n] )
// ---------------------------------------------------------------------------
__global__ __launch_bounds__(256) void gemm1_scale(
    const float* __restrict__ x,
    const float* __restrict__ W1,
    const float* __restrict__ dinv,
    unsigned int* __restrict__ h1b) {
    __shared__ float w[IN_CH * HID];   // 16 KB
    for (int i = threadIdx.x; i < IN_CH * HID; i += 256)
        w[i] = W1[i];
    __syncthreads();

    int node = blockIdx.x * 8 + (threadIdx.x >> 5);
    int c    = threadIdx.x & 31;
    if (node >= N_NODES) return;

    const float4* xr = reinterpret_cast<const float4*>(x + (size_t)node * IN_CH);
    float acc = 0.0f;
#pragma unroll
    for (int k4 = 0; k4 < IN_CH / 4; ++k4) {
        float4 v = xr[k4];
        acc += v.x * w[(k4 * 4 + 0) * HID + c]
             + v.y * w[(k4 * 4 + 1) * HID + c]
             + v.z * w[(k4 * 4 + 2) * HID + c]
             + v.w * w[(k4 * 4 + 3) * HID + c];
    }
    float val = acc * dinv[node];
    int c2 = c & 15;
    float lo = __shfl(val, 2 * c2, 32);
    float hi = __shfl(val, 2 * c2 + 1, 32);
    if (c < 16) h1b[(size_t)node * 16 + c2] = pack_bf16x2(lo, hi);
}

// ---------------------------------------------------------------------------
// Row-gather core (round-7 structure, contiguous per-half sub-ranges):
// each 16-lane half owns a CONTIGUOUS index range, so 4 edge indices come
// from ONE int4 col load (4B-aligned dwordx4 — legal on CDNA), removing the
// per-edge col-load -> gather dependency chain. 4 independent gathers in
// flight per lane. No cross-lane shfl in the loop (round-9's shfl
// distribution regressed: +15% time from issue overhead).
// ---------------------------------------------------------------------------
__device__ __forceinline__ void row_gather(
    const int* __restrict__ col, const unsigned int* __restrict__ tab,
    int s, int e, int c2,
    float aeA[4], float aoA[4]) {
    int ee = s;
    for (; ee + 4 <= e; ee += 4) {
        int4 c4 = *reinterpret_cast<const int4*>(col + ee);
        unsigned int v0 = tab[(size_t)c4.x * 16 + c2];
        unsigned int v1 = tab[(size_t)c4.y * 16 + c2];
        unsigned int v2 = tab[(size_t)c4.z * 16 + c2];
        unsigned int v3 = tab[(size_t)c4.w * 16 + c2];
        aeA[0] += bf_lo(v0); aoA[0] += bf_hi(v0);
        aeA[1] += bf_lo(v1); aoA[1] += bf_hi(v1);
        aeA[2] += bf_lo(v2); aoA[2] += bf_hi(v2);
        aeA[3] += bf_lo(v3); aoA[3] += bf_hi(v3);
    }
    for (; ee < e; ++ee) {
        unsigned int v = tab[(size_t)col[ee] * 16 + c2];
        aeA[1] += bf_lo(v); aoA[1] += bf_hi(v);
    }
}

// ---------------------------------------------------------------------------
// Layer-1 aggregate (bf16 gather) + relu + gemm2 (shuffles) -> h3b.
// ---------------------------------------------------------------------------
__global__ __launch_bounds__(256, 8) void aggregate1(
    const int* __restrict__ rowptr,
    const int* __restrict__ col,
    const unsigned int* __restrict__ h1b,
    const float* __restrict__ dinv,
    const float* __restrict__ b1,
    const float* __restrict__ W2,
    unsigned int* __restrict__ h3b) {
    __shared__ float w2s[HID * HID];   // 4 KB
    for (int i = threadIdx.x; i < HID * HID; i += 256)
        w2s[i] = W2[i];
    __syncthreads();

    int node = blockIdx.x * 8 + (threadIdx.x >> 5);
    int lane = threadIdx.x & 31;
    if (node >= N_NODES) return;
    int half = lane >> 4;
    int c2   = lane & 15;

    int e0 = rowptr[node];
    int e1 = rowptr[node + 1];
    int mid = e0 + ((e1 - e0) >> 1);
    float aeA[4] = {0.f, 0.f, 0.f, 0.f};
    float aoA[4] = {0.f, 0.f, 0.f, 0.f};
    if (half == 0) {                       // self-loop
        unsigned int sv = h1b[(size_t)node * 16 + c2];
        aeA[0] = bf_lo(sv); aoA[0] = bf_hi(sv);
    }
    row_gather(col, h1b, half ? mid : e0, half ? e1 : mid, c2, aeA, aoA);

    float ae = (aeA[0] + aeA[1]) + (aeA[2] + aeA[3]);
    float ao = (aoA[0] + aoA[1]) + (aoA[2] + aoA[3]);
    ae += __shfl_xor(ae, 16, 32);          // combine halves (all lanes active)
    ao += __shfl_xor(ao, 16, 32);

    float dn = dinv[node];
    float h2e = ae * dn + b1[2 * c2];      h2e = h2e > 0.f ? h2e : 0.f;
    float h2o = ao * dn + b1[2 * c2 + 1];  h2o = h2o > 0.f ? h2o : 0.f;

    // gemm2: lane j (half 0) holds h2[2j], h2[2j+1]; all-to-all via shfl
    float a2e = 0.f, a2o = 0.f;
#pragma unroll
    for (int j = 0; j < 16; ++j) {
        float he = __shfl(h2e, j, 32);     // h2[2j]
        float ho = __shfl(h2o, j, 32);     // h2[2j+1]
        a2e += he * w2s[(2 * j) * HID + 2 * c2]     + ho * w2s[(2 * j + 1) * HID + 2 * c2];
        a2o += he * w2s[(2 * j) * HID + 2 * c2 + 1] + ho * w2s[(2 * j + 1) * HID + 2 * c2 + 1];
    }
    if (half == 0)
        h3b[(size_t)node * 16 + c2] = pack_bf16x2(a2e * dn, a2o * dn);
}

// ---------------------------------------------------------------------------
// Layer-2 aggregate (bf16 gather) + epilogue2 -> f32 out
// ---------------------------------------------------------------------------
__global__ __launch_bounds__(256, 8) void aggregate2(
    const int* __restrict__ rowptr,
    const int* __restrict__ col,
    const unsigned int* __restrict__ h3b,
    const float* __restrict__ dinv,
    const float* __restrict__ b2,
    float2* __restrict__ out2) {
    int node = blockIdx.x * 8 + (threadIdx.x >> 5);
    int lane = threadIdx.x & 31;
    if (node >= N_NODES) return;
    int half = lane >> 4;
    int c2   = lane & 15;

    int e0 = rowptr[node];
    int e1 = rowptr[node + 1];
    int mid = e0 + ((e1 - e0) >> 1);
    float aeA[4] = {0.f, 0.f, 0.f, 0.f};
    float aoA[4] = {0.f, 0.f, 0.f, 0.f};
    if (half == 0) {                       // self-loop
        unsigned int sv = h3b[(size_t)node * 16 + c2];
        aeA[0] = bf_lo(sv); aoA[0] = bf_hi(sv);
    }
    row_gather(col, h3b, half ? mid : e0, half ? e1 : mid, c2, aeA, aoA);

    float ae = (aeA[0] + aeA[1]) + (aeA[2] + aeA[3]);
    float ao = (aoA[0] + aoA[1]) + (aoA[2] + aoA[3]);
    ae += __shfl_xor(ae, 16, 32);
    ao += __shfl_xor(ao, 16, 32);

    if (half == 0) {
        float dn = dinv[node];
        float2 o;
        o.x = ae * dn + b2[2 * c2];
        o.y = ao * dn + b2[2 * c2 + 1];
        out2[(size_t)node * 16 + c2] = o;
    }
}

// ---------------------------------------------------------------------------
extern "C" void kernel_launch(void* const* d_in, const int* in_sizes, int n_in,
                              void* d_out, int out_size, void* d_ws, size_t ws_size,
                              hipStream_t stream) {
    const float* x  = (const float*)d_in[0];
    const int*   ei = (const int*)d_in[1];
    const float* W1 = (const float*)d_in[2];
    const float* b1 = (const float*)d_in[3];
    const float* W2 = (const float*)d_in[4];
    const float* b2 = (const float*)d_in[5];
    float* out = (float*)d_out;

    // workspace: flag[64] | bcur[512] | rowptr[N+1] | col[E] | dinv[N] |
    //            region{ h1b (6.4MB) | h3b (6.4MB) } where ebuf
    //            (512*CAP u32 = 16 MiB) ALIASES the region (dead by gemm1).
    int*          flag   = (int*)d_ws;
    int*          bcur   = flag + 64;
    int*          rowptr = bcur + NB;
    int*          col    = rowptr + (N_NODES + 1);
    float*        dinv   = (float*)(col + N_EDGES);
    unsigned int* h1b    = (unsigned int*)(dinv + N_NODES);
    unsigned int* h3b    = h1b + (size_t)N_NODES * 16;
    unsigned int* ebuf   = h1b;                          // alias, dead by gemm1

    const int gemmBlocks  = (N_NODES + 7) / 8;               // 12500
    const int chunkBlocks = (N_EDGES + CHUNK - 1) / CHUNK;   // 391

    // bucketed CSR build (single pass over edge_index), 3 dispatches
    init_all<<<1, 512, 0, stream>>>(ei, flag, bcur);
    bucket_scatter2<<<chunkBlocks, 256, 0, stream>>>(ei, flag, bcur, ebuf);
    fill_csr3<<<NB, 256, 0, stream>>>(bcur, ebuf, rowptr, dinv, col);

    // layer 1 (+ fused relu + gemm2)
    gemm1_scale<<<gemmBlocks, 256, 0, stream>>>(x, W1, dinv, h1b);
    aggregate1<<<gemmBlocks, 256, 0, stream>>>(rowptr, col, h1b, dinv, b1, W2, h3b);

    // layer 2 (+ fused epilogue)
    aggregate2<<<gemmBlocks, 256, 0, stream>>>(rowptr, col, h3b, dinv, b2, (float2*)out);
}